// Round 9
// baseline (6466.093 us; speedup 1.0000x reference)
//
#include <hip/hip_runtime.h>
#include <cstdint>
#include <cstddef>

// ============================================================================
// Persistent fused 2-layer LSTM + FC for MI355X (gfx950) — Round 14:
// R13 (XCD-clustered pipeline, 2427us) + three measured trims:
//   1. LDS bank-conflict fix: kRowH 1048->1034 f16 (517 dwords, ODD stride:
//      m*517 mod 32 permutes bank starts; R9-proven 4.1M-conflict class;
//      R13's 524-dword stride piled 4-way = 118M conflict-cycles).
//      kRowX 264->266 likewise.
//   2. Per-wave tags: each producing wave stores its 128B record slice (sc1),
//      s_waitcnt vmcnt(0), posts its OWN tag dword (packed 64B line per
//      block). Tags flow as waves finish (not after all-waves + barrier);
//      one __syncthreads deleted per step. Consumers poll packed lines:
//      L0: 32 blk x 8 tags (2 u64/lane), L1: 64 blk x 4 tags (+L0's),
//      FC: 64 blk x 4 tags.
//   3. x double-buffer (parity t&1) keeps the x prefetch overlapped with the
//      poll despite the removed barrier (L0 = 2 barriers/step, L1 = 3).
// Everything else identical to R13: cluster roles (c0/c1 L0 scope-32,
// c2-c5 L1 scope-64 K-split, c6/c7 FC), relaxed sc1 records, plain cached
// staging (L2-dedup within XCD; fresh addresses per slot), in-lane gates.
// ============================================================================

#define NTHR 512

typedef _Float16 f16;
typedef _Float16 f16x8 __attribute__((ext_vector_type(8)));
typedef float f32x4 __attribute__((ext_vector_type(4)));
typedef unsigned long long u64;

namespace {
constexpr int kT = 512, kI = 256, kH = 1024, kO = 512, kTR = 500;
constexpr int kSteps = 500;
constexpr size_t kHalfSlot = 32768;              // 16 b x 1024 u x f16
// ws layout (bytes):
//   [0,4096):      L0 tags: half h at +h*2048, block rho line at rho*64,
//                  wave w dword at +w*4 (8 dwords = 32B used per line)
//   [4096,12288):  L1 tags: half h at +h*4096, block rank line at rank*64,
//                  kh1-wave dword at +(w-4)*4 (4 dwords used)
constexpr size_t kTagL0 = 0;
constexpr size_t kTagL1 = 4096;
constexpr size_t kH1Off = 16384;                 // [t][half][b:16][u:1024] f16
constexpr size_t kH2Off = kH1Off + 503ull * 2 * kHalfSlot;
// LDS geometry (f16 units). ODD dword strides -> conflict-free b128 reads.
constexpr int kRowH = 1034;                      // 517 dwords
constexpr int kRowX = 266;                       // 133 dwords
constexpr int kHBytes = 16 * kRowH * 2;          // 33088
constexpr int kXBytes = 16 * kRowX * 2;          // 8512 (x1 buffer)
// L1 is max: 2*kHBytes + zone 4*16*17*4 = 66176 + 4352
constexpr int kLdsBytes = 2 * kHBytes + 4 * 16 * 17 * 4;  // 70528
}

__device__ __forceinline__ u64 ld_tag64(const void* p) {
  return __hip_atomic_load((const u64*)p, __ATOMIC_RELAXED,
                           __HIP_MEMORY_SCOPE_AGENT);
}
__device__ __forceinline__ void st_tag(void* p, unsigned v) {
  __hip_atomic_store((unsigned*)p, v, __ATOMIC_RELAXED,
                     __HIP_MEMORY_SCOPE_AGENT);
}
__device__ __forceinline__ void st_rec_u64(void* p, u64 v) {
  __hip_atomic_store((u64*)p, v, __ATOMIC_RELAXED, __HIP_MEMORY_SCOPE_AGENT);
}
__device__ __forceinline__ bool tag4_ge(u64 a, u64 b, unsigned t) {
  return ((unsigned)a >= t) && ((unsigned)(a >> 32) >= t) &&
         ((unsigned)b >= t) && ((unsigned)(b >> 32) >= t);
}
__device__ __forceinline__ float sigmoid_f(float x) {
  return __builtin_amdgcn_rcpf(1.f + __expf(-x));
}
__device__ __forceinline__ float tanh_f(float x) {
  return 1.f - 2.f * __builtin_amdgcn_rcpf(1.f + __expf(2.f * x));
}
__device__ __forceinline__ f16x8 load8(const float* p) {
  f16x8 r;
#pragma unroll
  for (int j = 0; j < 8; ++j) r[j] = (f16)p[j];
  return r;
}
// pack 4 per-lane f16 h-values (lanes lg=0..3 over the same b) into one u64
__device__ __forceinline__ u64 pack4(float h, int lg) {
  f16 hv = (f16)h;
  unsigned short us;
  __builtin_memcpy(&us, &hv, 2);
  unsigned own = us;
  unsigned o1 = __shfl_xor((int)own, 16);
  unsigned p32 = (lg & 1) ? ((o1 & 0xffffu) | (own << 16))
                          : ((own & 0xffffu) | (o1 << 16));
  unsigned o2 = (unsigned)__shfl_xor((int)p32, 32);
  return (lg & 2) ? ((u64)o2 | ((u64)p32 << 32))
                  : ((u64)p32 | ((u64)o2 << 32));
}

__global__ void __launch_bounds__(256, 1) lstm_init_kernel(char* ws) {
  const int gid = blockIdx.x * 256 + threadIdx.x;   // 32768 threads
  unsigned* f = (unsigned*)ws;
  if (gid < 4096) f[gid] = 0u;                      // all tag regions
  u64* r1 = (u64*)(ws + kH1Off);                    // slot 0, both halves
  u64* r2 = (u64*)(ws + kH2Off);
  if (gid < 8192) { r1[gid] = 0ull; r2[gid] = 0ull; }
}

__global__ void __launch_bounds__(NTHR, 1) __attribute__((amdgpu_waves_per_eu(2)))
lstm_pipe_kernel(const float* __restrict__ x,
                 const float* __restrict__ Wih0, const float* __restrict__ Whh0,
                 const float* __restrict__ bih0, const float* __restrict__ bhh0,
                 const float* __restrict__ Wih1, const float* __restrict__ Whh1,
                 const float* __restrict__ bih1, const float* __restrict__ bhh1,
                 const float* __restrict__ Wfc, const float* __restrict__ bfc,
                 float* __restrict__ out, char* __restrict__ ws) {
  const int tid = threadIdx.x;
  const int bk = blockIdx.x;
  const int w = tid >> 6;
  const int lane = tid & 63;
  const int m = lane & 15;                  // A row idx / B col (=batch) / D col
  const int kg = lane >> 4;                 // k-group for A/B frags
  const int lg = lane >> 4;                 // D row group
  const int c = bk & 7, rho = bk >> 3;
  extern __shared__ char smem[];

  if (c < 2) {
    // ===================== L0: h1 recurrence, scope 32 =====================
    const int half = c;
    const int q = m >> 2, g = m & 3;
    const int uA = rho * 32 + 4 * w + q;    // A-row unit
    const int uD = rho * 32 + 4 * w + lg;   // D-row unit (gate math/store)
    f16x8 whh[32], wih[8];
#pragma unroll
    for (int kc = 0; kc < 32; ++kc)
      whh[kc] = load8(Whh0 + (size_t)(g * kH + uA) * kH + kc * 32 + kg * 8);
#pragma unroll
    for (int kx = 0; kx < 8; ++kx)
      wih[kx] = load8(Wih0 + (size_t)(g * kH + uA) * kI + kx * 32 + kg * 8);
    float bias[4];
#pragma unroll
    for (int j = 0; j < 4; ++j) bias[j] = bih0[j * kH + uD] + bhh0[j * kH + uD];
    float cst = 0.f;
    f16* ldsH = (f16*)smem;                             // [16][1034]
    f16* ldsX0 = (f16*)(smem + kHBytes);                // x buf parity 0
    f16* ldsX1 = (f16*)(smem + kHBytes + kXBytes);      // x buf parity 1
    char* tagLine = ws + kTagL0 + (size_t)half * 2048 + (size_t)rho * 64;
    const u64* tpoll = (const u64*)(ws + kTagL0 + (size_t)half * 2048 +
                                    (size_t)(lane >> 1) * 64 +
                                    (size_t)(lane & 1) * 16);
    const int xb = tid >> 5, xcol = (tid & 31) * 8;
    const int sb = tid >> 7, so = (tid & 127) * 8;      // h-stage LDS dest

    for (int t = 1; t <= kSteps; ++t) {
      f16* ldsX = (t & 1) ? ldsX1 : ldsX0;
      {                                     // x slice -> LDS (tag-independent)
        f16x8 xv = load8(x + ((size_t)(half * 16 + xb) * kT + (t - 1)) * kI + xcol);
        *(f16x8*)(ldsX + xb * kRowX + xcol) = xv;
      }
      if (w == 7) {                         // poll own cluster: h1[t-1] ready
        const unsigned tgt = (unsigned)(t - 1);
        bool done;
        do {
          u64 a = ld_tag64(tpoll), b = ld_tag64(tpoll + 1);
          done = __all((int)tag4_ge(a, b, tgt));
          if (!done) __builtin_amdgcn_s_sleep(1);
        } while (!done);
      }
      __syncthreads();                      // SYNC_P: tags observed
      {                                     // stage h1[t-1] 32KB -> LDS
        const char* rec = ws + kH1Off + ((size_t)(t - 1) * 2 + half) * kHalfSlot;
        f16x8 h0 = *(const f16x8*)(rec + (size_t)tid * 16);
        f16x8 h1v = *(const f16x8*)(rec + (size_t)(tid + 512) * 16);
        f16x8 h2v = *(const f16x8*)(rec + (size_t)(tid + 1024) * 16);
        f16x8 h3v = *(const f16x8*)(rec + (size_t)(tid + 1536) * 16);
        *(f16x8*)(ldsH + (sb + 0) * kRowH + so) = h0;
        *(f16x8*)(ldsH + (sb + 4) * kRowH + so) = h1v;
        *(f16x8*)(ldsH + (sb + 8) * kRowH + so) = h2v;
        *(f16x8*)(ldsH + (sb + 12) * kRowH + so) = h3v;
      }
      __syncthreads();                      // SYNC_S: stage complete
      f32x4 acc = {0.f, 0.f, 0.f, 0.f};
#pragma unroll
      for (int kc = 0; kc < 32; ++kc) {
        f16x8 bf = *(const f16x8*)(ldsH + m * kRowH + kc * 32 + kg * 8);
        acc = __builtin_amdgcn_mfma_f32_16x16x32_f16(whh[kc], bf, acc, 0, 0, 0);
      }
#pragma unroll
      for (int kx = 0; kx < 8; ++kx) {
        f16x8 bf = *(const f16x8*)(ldsX + m * kRowX + kx * 32 + kg * 8);
        acc = __builtin_amdgcn_mfma_f32_16x16x32_f16(wih[kx], bf, acc, 0, 0, 0);
      }
      // gates (lane holds 4 gates of unit uD, batch m)
      const float pi = acc[0] + bias[0], pf = acc[1] + bias[1];
      const float pg = acc[2] + bias[2], po = acc[3] + bias[3];
      cst = sigmoid_f(pf) * cst + sigmoid_f(pi) * tanh_f(pg);
      const float h = sigmoid_f(po) * tanh_f(cst);
      const u64 pk = pack4(h, lg);
      if (lane < 16) {                      // b = lane, units rho*32+4w..+3
        st_rec_u64(ws + kH1Off + ((size_t)t * 2 + half) * kHalfSlot +
                       (size_t)lane * 2048 + (size_t)(rho * 32 + 4 * w) * 2,
                   pk);
      }
      asm volatile("s_waitcnt vmcnt(0)" ::: "memory");  // this wave's record
      if (lane == 0) st_tag(tagLine + w * 4, (unsigned)t);  // per-wave tag
    }

  } else if (c < 6) {
    // ===================== L1: h2 recurrence, scope 64 =====================
    const int half = c & 1;
    const int rank = rho + ((c >= 4) ? 32 : 0);   // 0..63
    const int u0 = rank * 16;
    const int rg = w & 3, kh = w >> 2;            // row-group / K-half
    const int q = m >> 2, g = m & 3;
    const int uA = u0 + 4 * rg + q;
    const int uD = u0 + 4 * rg + lg;
    const float* WA = kh ? Whh1 : Wih1;
    f16x8 wa[32];
#pragma unroll
    for (int kc = 0; kc < 32; ++kc)
      wa[kc] = load8(WA + (size_t)(g * kH + uA) * kH + kc * 32 + kg * 8);
    float bias[4];
#pragma unroll
    for (int j = 0; j < 4; ++j) bias[j] = bih1[j * kH + uD] + bhh1[j * kH + uD];
    float cst = 0.f;                              // live on kh==1 waves
    f16* ldsH1 = (f16*)smem;                      // [16][1034] h1[t]
    f16* ldsH2 = (f16*)(smem + kHBytes);          // [16][1034] h2[t-1]
    float* zone = (float*)(smem + 2 * kHBytes);   // [4][16][17]
    char* tagLine = ws + kTagL1 + (size_t)half * 4096 + (size_t)rank * 64;
    const u64* tpB = (const u64*)(ws + kTagL1 + (size_t)half * 4096 +
                                  (size_t)lane * 64);
    const u64* tpA = (const u64*)(ws + kTagL0 + (size_t)half * 2048 +
                                  (size_t)(lane >> 1) * 64 +
                                  (size_t)(lane & 1) * 16);
    const int sb = tid >> 7, so = (tid & 127) * 8;

    for (int t = 1; t <= kSteps; ++t) {
      if (w == 7) {                         // h1[t] from L0, h2[t-1] own group
        const unsigned tgtA = (unsigned)t, tgtB = (unsigned)(t - 1);
        bool done;
        do {
          u64 b0 = ld_tag64(tpB);           // own 4 kh1-tags (dwords 0-3)
          u64 b1 = ld_tag64(tpB + 1);
          u64 a0 = ld_tag64(tpA);           // L0 4 wave-tags
          u64 a1 = ld_tag64(tpA + 1);
          bool ok = tag4_ge(b0, b1, tgtB) && tag4_ge(a0, a1, tgtA);
          done = __all((int)ok);
          if (!done) __builtin_amdgcn_s_sleep(1);
        } while (!done);
      }
      __syncthreads();                      // SYNC_P
      {                                     // stage h1[t] + h2[t-1]
        const char* r1 = ws + kH1Off + ((size_t)t * 2 + half) * kHalfSlot;
        const char* r2 = ws + kH2Off + ((size_t)(t - 1) * 2 + half) * kHalfSlot;
        f16x8 a0 = *(const f16x8*)(r1 + (size_t)tid * 16);
        f16x8 a1 = *(const f16x8*)(r1 + (size_t)(tid + 512) * 16);
        f16x8 a2 = *(const f16x8*)(r1 + (size_t)(tid + 1024) * 16);
        f16x8 a3 = *(const f16x8*)(r1 + (size_t)(tid + 1536) * 16);
        f16x8 b0 = *(const f16x8*)(r2 + (size_t)tid * 16);
        f16x8 b1 = *(const f16x8*)(r2 + (size_t)(tid + 512) * 16);
        f16x8 b2 = *(const f16x8*)(r2 + (size_t)(tid + 1024) * 16);
        f16x8 b3 = *(const f16x8*)(r2 + (size_t)(tid + 1536) * 16);
        *(f16x8*)(ldsH1 + (sb + 0) * kRowH + so) = a0;
        *(f16x8*)(ldsH1 + (sb + 4) * kRowH + so) = a1;
        *(f16x8*)(ldsH1 + (sb + 8) * kRowH + so) = a2;
        *(f16x8*)(ldsH1 + (sb + 12) * kRowH + so) = a3;
        *(f16x8*)(ldsH2 + (sb + 0) * kRowH + so) = b0;
        *(f16x8*)(ldsH2 + (sb + 4) * kRowH + so) = b1;
        *(f16x8*)(ldsH2 + (sb + 8) * kRowH + so) = b2;
        *(f16x8*)(ldsH2 + (sb + 12) * kRowH + so) = b3;
      }
      __syncthreads();                      // SYNC_S
      const f16* ldsB = kh ? ldsH2 : ldsH1;
      f32x4 acc = {0.f, 0.f, 0.f, 0.f};
#pragma unroll
      for (int kc = 0; kc < 32; ++kc) {
        f16x8 bf = *(const f16x8*)(ldsB + m * kRowH + kc * 32 + kg * 8);
        acc = __builtin_amdgcn_mfma_f32_16x16x32_f16(wa[kc], bf, acc, 0, 0, 0);
      }
      if (kh == 0) {                        // publish h1-part partials
#pragma unroll
        for (int j = 0; j < 4; ++j)
          zone[(rg * 16 + lg * 4 + j) * 17 + m] = acc[j];
      }
      __syncthreads();                      // SYNC_Z: zone ready
      if (kh == 1) {                        // combine + gates + store + tag
        const float pi = acc[0] + zone[(rg * 16 + lg * 4 + 0) * 17 + m] + bias[0];
        const float pf = acc[1] + zone[(rg * 16 + lg * 4 + 1) * 17 + m] + bias[1];
        const float pg = acc[2] + zone[(rg * 16 + lg * 4 + 2) * 17 + m] + bias[2];
        const float po = acc[3] + zone[(rg * 16 + lg * 4 + 3) * 17 + m] + bias[3];
        cst = sigmoid_f(pf) * cst + sigmoid_f(pi) * tanh_f(pg);
        const float h = sigmoid_f(po) * tanh_f(cst);
        const u64 pk = pack4(h, lg);
        if (lane < 16) {
          st_rec_u64(ws + kH2Off + ((size_t)t * 2 + half) * kHalfSlot +
                         (size_t)lane * 2048 + (size_t)(u0 + 4 * rg) * 2,
                     pk);
        }
        asm volatile("s_waitcnt vmcnt(0)" ::: "memory");
        if (lane == 0) st_tag(tagLine + (w - 4) * 4, (unsigned)t);
      }
    }

  } else {
    // ===================== FC: out = Wfc @ h2[t] + b =======================
    const int half = c - 6;
    const int o0 = rho * 16;
    f16x8 wf[4];
#pragma unroll
    for (int i = 0; i < 4; ++i)
      wf[i] = load8(Wfc + (size_t)(o0 + m) * kH + (size_t)(w + 8 * i) * 32 + kg * 8);
    f16* ldsH = (f16*)smem;                        // [16][1034] h2[t]
    float* zone = (float*)(smem + kHBytes);        // [8][16][17] per-wave
    const u64* tpB = (const u64*)(ws + kTagL1 + (size_t)half * 4096 +
                                  (size_t)lane * 64);
    const int sb = tid >> 7, so = (tid & 127) * 8;
    const int ob = lane >> 2, op = lane & 3;
    float4 bf4;
    if (w == 0) bf4 = *(const float4*)(bfc + o0 + op * 4);

    for (int t = 1; t <= kSteps; ++t) {
      if (w == 7) {
        const unsigned tgt = (unsigned)t;
        bool done;
        do {
          u64 b0 = ld_tag64(tpB), b1 = ld_tag64(tpB + 1);
          done = __all((int)tag4_ge(b0, b1, tgt));
          if (!done) __builtin_amdgcn_s_sleep(1);
        } while (!done);
      }
      __syncthreads();
      {
        const char* r2 = ws + kH2Off + ((size_t)t * 2 + half) * kHalfSlot;
        f16x8 b0 = *(const f16x8*)(r2 + (size_t)tid * 16);
        f16x8 b1 = *(const f16x8*)(r2 + (size_t)(tid + 512) * 16);
        f16x8 b2 = *(const f16x8*)(r2 + (size_t)(tid + 1024) * 16);
        f16x8 b3 = *(const f16x8*)(r2 + (size_t)(tid + 1536) * 16);
        *(f16x8*)(ldsH + (sb + 0) * kRowH + so) = b0;
        *(f16x8*)(ldsH + (sb + 4) * kRowH + so) = b1;
        *(f16x8*)(ldsH + (sb + 8) * kRowH + so) = b2;
        *(f16x8*)(ldsH + (sb + 12) * kRowH + so) = b3;
      }
      __syncthreads();
      f32x4 acc = {0.f, 0.f, 0.f, 0.f};
#pragma unroll
      for (int i = 0; i < 4; ++i) {
        f16x8 bf = *(const f16x8*)(ldsH + m * kRowH + (w + 8 * i) * 32 + kg * 8);
        acc = __builtin_amdgcn_mfma_f32_16x16x32_f16(wf[i], bf, acc, 0, 0, 0);
      }
#pragma unroll
      for (int j = 0; j < 4; ++j)
        zone[(w * 16 + lg * 4 + j) * 17 + m] = acc[j];    // per-wave slice
      __syncthreads();
      if (w == 0) {                          // sum 8 slices, + bias, store
        float4 v;
#pragma unroll
        for (int jj = 0; jj < 4; ++jj) {
          float s = 0.f;
#pragma unroll
          for (int ww = 0; ww < 8; ++ww)
            s += zone[(ww * 16 + op * 4 + jj) * 17 + ob];
          ((float*)&v)[jj] = s + ((const float*)&bf4)[jj];
        }
        *(float4*)(out + ((size_t)(half * 16 + ob) * kTR + (t - 1)) * kO +
                   o0 + op * 4) = v;
      }
    }
  }
}

extern "C" void kernel_launch(void* const* d_in, const int* in_sizes, int n_in,
                              void* d_out, int out_size, void* d_ws,
                              size_t ws_size, hipStream_t stream) {
  const float* x    = (const float*)d_in[0];
  const float* Wih0 = (const float*)d_in[1];
  const float* Whh0 = (const float*)d_in[2];
  const float* bih0 = (const float*)d_in[3];
  const float* bhh0 = (const float*)d_in[4];
  const float* Wih1 = (const float*)d_in[5];
  const float* Whh1 = (const float*)d_in[6];
  const float* bih1 = (const float*)d_in[7];
  const float* bhh1 = (const float*)d_in[8];
  const float* Wfc  = (const float*)d_in[9];
  const float* bfc  = (const float*)d_in[10];
  float* out = (float*)d_out;
  char* ws   = (char*)d_ws;

  (void)hipFuncSetAttribute((const void*)lstm_pipe_kernel,
                            hipFuncAttributeMaxDynamicSharedMemorySize,
                            kLdsBytes);

  hipLaunchKernelGGL(lstm_init_kernel, dim3(128), dim3(256), 0, stream, ws);
  hipLaunchKernelGGL(lstm_pipe_kernel, dim3(256), dim3(NTHR), kLdsBytes,
                     stream, x, Wih0, Whh0, bih0, bhh0, Wih1, Whh1, bih1,
                     bhh1, Wfc, bfc, out, ws);
}

// Round 10
// 6286.956 us; speedup vs baseline: 1.0285x; 1.0285x over previous
//
#include <hip/hip_runtime.h>
#include <cstdint>
#include <cstddef>

// ============================================================================
// Persistent fused 2-layer LSTM + FC for MI355X (gfx950) — Round 15:
// R13 baseline (2427us) + ISOLATED bank-conflict fix. R14 post-mortem:
// bundled changes separated by counters — bank fix GOOD (conflicts 118.8M ->
// 8.2M), per-wave tags BAD (8 writers/line/step + cross-XCD pollers => LLC
// hot-line serialization; 2.7x regression + 34ms outlier; same class as R8).
// Rule (twice-confirmed): single writer per sync line, aggregated polling.
// Changes vs R13 (ONLY these):
//   kRowH 1048 -> 1034 f16 (517 dwords, odd => m*517 mod 32 permutes
//   ds_read_b128 bank starts; worst-case 2-way = free). kRowX 264 -> 266.
// Everything else == R13: cluster roles (c0/c1 L0 scope-32 in-lane gates,
// c2-c5 L1 scope-64 K-split, c6/c7 FC), single tag dword per block posted by
// tid0 after the end-of-step barrier, sc1 relaxed records, plain cached
// staging, steps t=1..500.
// ============================================================================

#define NTHR 512

typedef _Float16 f16;
typedef _Float16 f16x8 __attribute__((ext_vector_type(8)));
typedef float f32x4 __attribute__((ext_vector_type(4)));
typedef unsigned long long u64;

namespace {
constexpr int kT = 512, kI = 256, kH = 1024, kO = 512, kTR = 500;
constexpr int kSteps = 500;
constexpr size_t kHalfSlot = 32768;              // 16 b x 1024 u x f16
// ws layout (bytes):
//   [0,2048):        L0 tags half0  (32 x 64B stride)
//   [2048,4096):     L0 tags half1
//   [4096,8192):     L1 tags half0  (64 x 64B stride)
//   [8192,12288):    L1 tags half1
constexpr size_t kTagL0 = 0;
constexpr size_t kTagL1 = 4096;
constexpr size_t kH1Off = 16384;                 // [t][half][b:16][u:1024] f16
constexpr size_t kH2Off = kH1Off + 503ull * 2 * kHalfSlot;
// LDS geometry (f16). ODD dword strides -> conflict-free-ish b128 reads.
constexpr int kRowH = 1034;                      // 517 dwords (was 1048/524)
constexpr int kRowX = 266;                       // 133 dwords (was 264/132)
constexpr int kHBytes = 16 * kRowH * 2;          // 33088
constexpr int kLdsBytes = 2 * kHBytes + 4 * 16 * 17 * 4;  // 70528 (L1 max)
}

__device__ __forceinline__ unsigned ld_tag(const void* p) {
  return __hip_atomic_load((const unsigned*)p, __ATOMIC_RELAXED,
                           __HIP_MEMORY_SCOPE_AGENT);
}
__device__ __forceinline__ void st_tag(void* p, unsigned v) {
  __hip_atomic_store((unsigned*)p, v, __ATOMIC_RELAXED,
                     __HIP_MEMORY_SCOPE_AGENT);
}
__device__ __forceinline__ void st_rec_u64(void* p, u64 v) {
  __hip_atomic_store((u64*)p, v, __ATOMIC_RELAXED, __HIP_MEMORY_SCOPE_AGENT);
}
__device__ __forceinline__ float sigmoid_f(float x) {
  return __builtin_amdgcn_rcpf(1.f + __expf(-x));
}
__device__ __forceinline__ float tanh_f(float x) {
  return 1.f - 2.f * __builtin_amdgcn_rcpf(1.f + __expf(2.f * x));
}
__device__ __forceinline__ f16x8 load8(const float* p) {
  f16x8 r;
#pragma unroll
  for (int j = 0; j < 8; ++j) r[j] = (f16)p[j];
  return r;
}
// pack 4 per-lane f16 h-values (lanes lg=0..3 over the same b) into one u64
__device__ __forceinline__ u64 pack4(float h, int lg) {
  f16 hv = (f16)h;
  unsigned short us;
  __builtin_memcpy(&us, &hv, 2);
  unsigned own = us;
  unsigned o1 = __shfl_xor((int)own, 16);
  unsigned p32 = (lg & 1) ? ((o1 & 0xffffu) | (own << 16))
                          : ((own & 0xffffu) | (o1 << 16));
  unsigned o2 = (unsigned)__shfl_xor((int)p32, 32);
  return (lg & 2) ? ((u64)o2 | ((u64)p32 << 32))
                  : ((u64)p32 | ((u64)o2 << 32));
}

__global__ void __launch_bounds__(256, 1) lstm_init_kernel(char* ws) {
  const int gid = blockIdx.x * 256 + threadIdx.x;   // 32768 threads
  unsigned* f = (unsigned*)ws;
  if (gid < 4096) f[gid] = 0u;                      // all tag regions
  u64* r1 = (u64*)(ws + kH1Off);                    // slot 0, both halves
  u64* r2 = (u64*)(ws + kH2Off);
  if (gid < 8192) { r1[gid] = 0ull; r2[gid] = 0ull; }
}

__global__ void __launch_bounds__(NTHR, 1) __attribute__((amdgpu_waves_per_eu(2)))
lstm_pipe_kernel(const float* __restrict__ x,
                 const float* __restrict__ Wih0, const float* __restrict__ Whh0,
                 const float* __restrict__ bih0, const float* __restrict__ bhh0,
                 const float* __restrict__ Wih1, const float* __restrict__ Whh1,
                 const float* __restrict__ bih1, const float* __restrict__ bhh1,
                 const float* __restrict__ Wfc, const float* __restrict__ bfc,
                 float* __restrict__ out, char* __restrict__ ws) {
  const int tid = threadIdx.x;
  const int bk = blockIdx.x;
  const int w = tid >> 6;
  const int lane = tid & 63;
  const int m = lane & 15;                  // A row idx / B col (=batch) / D col
  const int kg = lane >> 4;                 // k-group for A/B frags
  const int lg = lane >> 4;                 // D row group
  const int c = bk & 7, rho = bk >> 3;
  extern __shared__ char smem[];

  if (c < 2) {
    // ===================== L0: h1 recurrence, scope 32 =====================
    const int half = c;
    const int q = m >> 2, g = m & 3;
    const int uA = rho * 32 + 4 * w + q;    // A-row unit
    const int uD = rho * 32 + 4 * w + lg;   // D-row unit (gate math/store)
    f16x8 whh[32], wih[8];
#pragma unroll
    for (int kc = 0; kc < 32; ++kc)
      whh[kc] = load8(Whh0 + (size_t)(g * kH + uA) * kH + kc * 32 + kg * 8);
#pragma unroll
    for (int kx = 0; kx < 8; ++kx)
      wih[kx] = load8(Wih0 + (size_t)(g * kH + uA) * kI + kx * 32 + kg * 8);
    float bias[4];
#pragma unroll
    for (int j = 0; j < 4; ++j) bias[j] = bih0[j * kH + uD] + bhh0[j * kH + uD];
    float cst = 0.f;
    f16* ldsH = (f16*)smem;                             // [16][1034]
    f16* ldsX = (f16*)(smem + kHBytes);                 // [16][266]
    unsigned* tagMy = (unsigned*)(ws + kTagL0 + (size_t)half * 2048);
    const int xb = tid >> 5, xcol = (tid & 31) * 8;
    const int sb = tid >> 7, so = (tid & 127) * 8;      // h-stage LDS dest

    for (int t = 1; t <= kSteps; ++t) {
      if (w == 7) {                         // poll own cluster: h1[t-1] ready
        const unsigned tgt = (unsigned)(t - 1);
        const unsigned* tp = tagMy + (size_t)(lane & 31) * 16;
        bool done;
        do {
          done = __all((int)(ld_tag(tp) >= tgt));
          if (!done) __builtin_amdgcn_s_sleep(1);
        } while (!done);
      }
      {                                     // x slice -> LDS (tag-independent)
        f16x8 xv = load8(x + ((size_t)(half * 16 + xb) * kT + (t - 1)) * kI + xcol);
        *(f16x8*)(ldsX + xb * kRowX + xcol) = xv;
      }
      __syncthreads();                      // tags observed by whole block
      {                                     // stage h1[t-1] 32KB -> LDS
        const char* rec = ws + kH1Off + ((size_t)(t - 1) * 2 + half) * kHalfSlot;
        f16x8 h0 = *(const f16x8*)(rec + (size_t)tid * 16);
        f16x8 h1v = *(const f16x8*)(rec + (size_t)(tid + 512) * 16);
        f16x8 h2v = *(const f16x8*)(rec + (size_t)(tid + 1024) * 16);
        f16x8 h3v = *(const f16x8*)(rec + (size_t)(tid + 1536) * 16);
        *(f16x8*)(ldsH + (sb + 0) * kRowH + so) = h0;
        *(f16x8*)(ldsH + (sb + 4) * kRowH + so) = h1v;
        *(f16x8*)(ldsH + (sb + 8) * kRowH + so) = h2v;
        *(f16x8*)(ldsH + (sb + 12) * kRowH + so) = h3v;
      }
      __syncthreads();
      f32x4 acc = {0.f, 0.f, 0.f, 0.f};
#pragma unroll
      for (int kc = 0; kc < 32; ++kc) {
        f16x8 bf = *(const f16x8*)(ldsH + m * kRowH + kc * 32 + kg * 8);
        acc = __builtin_amdgcn_mfma_f32_16x16x32_f16(whh[kc], bf, acc, 0, 0, 0);
      }
#pragma unroll
      for (int kx = 0; kx < 8; ++kx) {
        f16x8 bf = *(const f16x8*)(ldsX + m * kRowX + kx * 32 + kg * 8);
        acc = __builtin_amdgcn_mfma_f32_16x16x32_f16(wih[kx], bf, acc, 0, 0, 0);
      }
      // gates (lane holds 4 gates of unit uD, batch m)
      const float pi = acc[0] + bias[0], pf = acc[1] + bias[1];
      const float pg = acc[2] + bias[2], po = acc[3] + bias[3];
      cst = sigmoid_f(pf) * cst + sigmoid_f(pi) * tanh_f(pg);
      const float h = sigmoid_f(po) * tanh_f(cst);
      const u64 pk = pack4(h, lg);
      if (lane < 16) {                      // b = lane, units rho*32+4w..+3
        st_rec_u64(ws + kH1Off + ((size_t)t * 2 + half) * kHalfSlot +
                       (size_t)lane * 2048 + (size_t)(rho * 32 + 4 * w) * 2,
                   pk);
        asm volatile("s_waitcnt vmcnt(0)" ::: "memory");
      }
      __syncthreads();                      // all waves' records drained
      if (tid == 0) st_tag(tagMy + (size_t)rho * 16, (unsigned)t);
    }

  } else if (c < 6) {
    // ===================== L1: h2 recurrence, scope 64 =====================
    const int half = c & 1;
    const int rank = rho + ((c >= 4) ? 32 : 0);   // 0..63
    const int u0 = rank * 16;
    const int rg = w & 3, kh = w >> 2;            // row-group / K-half
    const int q = m >> 2, g = m & 3;
    const int uA = u0 + 4 * rg + q;
    const int uD = u0 + 4 * rg + lg;
    const float* WA = kh ? Whh1 : Wih1;
    f16x8 wa[32];
#pragma unroll
    for (int kc = 0; kc < 32; ++kc)
      wa[kc] = load8(WA + (size_t)(g * kH + uA) * kH + kc * 32 + kg * 8);
    float bias[4];
#pragma unroll
    for (int j = 0; j < 4; ++j) bias[j] = bih1[j * kH + uD] + bhh1[j * kH + uD];
    float cst = 0.f;                              // live on kh==1 waves
    f16* ldsH1 = (f16*)smem;                      // [16][1034] h1[t]
    f16* ldsH2 = (f16*)(smem + kHBytes);          // [16][1034] h2[t-1]
    float* zone = (float*)(smem + 2 * kHBytes);   // [4][16][17]
    unsigned* tagL0h = (unsigned*)(ws + kTagL0 + (size_t)half * 2048);
    unsigned* tagL1h = (unsigned*)(ws + kTagL1 + (size_t)half * 4096);
    const int sb = tid >> 7, so = (tid & 127) * 8;

    for (int t = 1; t <= kSteps; ++t) {
      if (w == 7) {                         // h1[t] from L0, h2[t-1] own group
        const unsigned tgtA = (unsigned)t, tgtB = (unsigned)(t - 1);
        const unsigned* tpB = tagL1h + (size_t)lane * 16;
        const unsigned* tpA = tagL0h + (size_t)(lane & 31) * 16;
        bool done;
        do {
          bool ok = (ld_tag(tpB) >= tgtB);
          if (lane < 32) ok = ok && (ld_tag(tpA) >= tgtA);
          done = __all((int)ok);
          if (!done) __builtin_amdgcn_s_sleep(1);
        } while (!done);
      }
      __syncthreads();
      {                                     // stage h1[t] + h2[t-1]
        const char* r1 = ws + kH1Off + ((size_t)t * 2 + half) * kHalfSlot;
        const char* r2 = ws + kH2Off + ((size_t)(t - 1) * 2 + half) * kHalfSlot;
        f16x8 a0 = *(const f16x8*)(r1 + (size_t)tid * 16);
        f16x8 a1 = *(const f16x8*)(r1 + (size_t)(tid + 512) * 16);
        f16x8 a2 = *(const f16x8*)(r1 + (size_t)(tid + 1024) * 16);
        f16x8 a3 = *(const f16x8*)(r1 + (size_t)(tid + 1536) * 16);
        f16x8 b0 = *(const f16x8*)(r2 + (size_t)tid * 16);
        f16x8 b1 = *(const f16x8*)(r2 + (size_t)(tid + 512) * 16);
        f16x8 b2 = *(const f16x8*)(r2 + (size_t)(tid + 1024) * 16);
        f16x8 b3 = *(const f16x8*)(r2 + (size_t)(tid + 1536) * 16);
        *(f16x8*)(ldsH1 + (sb + 0) * kRowH + so) = a0;
        *(f16x8*)(ldsH1 + (sb + 4) * kRowH + so) = a1;
        *(f16x8*)(ldsH1 + (sb + 8) * kRowH + so) = a2;
        *(f16x8*)(ldsH1 + (sb + 12) * kRowH + so) = a3;
        *(f16x8*)(ldsH2 + (sb + 0) * kRowH + so) = b0;
        *(f16x8*)(ldsH2 + (sb + 4) * kRowH + so) = b1;
        *(f16x8*)(ldsH2 + (sb + 8) * kRowH + so) = b2;
        *(f16x8*)(ldsH2 + (sb + 12) * kRowH + so) = b3;
      }
      __syncthreads();
      const f16* ldsB = kh ? ldsH2 : ldsH1;
      f32x4 acc = {0.f, 0.f, 0.f, 0.f};
#pragma unroll
      for (int kc = 0; kc < 32; ++kc) {
        f16x8 bf = *(const f16x8*)(ldsB + m * kRowH + kc * 32 + kg * 8);
        acc = __builtin_amdgcn_mfma_f32_16x16x32_f16(wa[kc], bf, acc, 0, 0, 0);
      }
      if (kh == 0) {                        // publish h1-part partials
#pragma unroll
        for (int j = 0; j < 4; ++j)
          zone[(rg * 16 + lg * 4 + j) * 17 + m] = acc[j];
      }
      __syncthreads();                      // zone ready
      if (kh == 1) {                        // combine + gates + store
        const float pi = acc[0] + zone[(rg * 16 + lg * 4 + 0) * 17 + m] + bias[0];
        const float pf = acc[1] + zone[(rg * 16 + lg * 4 + 1) * 17 + m] + bias[1];
        const float pg = acc[2] + zone[(rg * 16 + lg * 4 + 2) * 17 + m] + bias[2];
        const float po = acc[3] + zone[(rg * 16 + lg * 4 + 3) * 17 + m] + bias[3];
        cst = sigmoid_f(pf) * cst + sigmoid_f(pi) * tanh_f(pg);
        const float h = sigmoid_f(po) * tanh_f(cst);
        const u64 pk = pack4(h, lg);
        if (lane < 16) {
          st_rec_u64(ws + kH2Off + ((size_t)t * 2 + half) * kHalfSlot +
                         (size_t)lane * 2048 + (size_t)(u0 + 4 * rg) * 2,
                     pk);
          asm volatile("s_waitcnt vmcnt(0)" ::: "memory");
        }
      }
      __syncthreads();                      // records drained
      if (tid == 0) st_tag(tagL1h + (size_t)rank * 16, (unsigned)t);
    }

  } else {
    // ===================== FC: out = Wfc @ h2[t] + b =======================
    const int half = c - 6;
    const int o0 = rho * 16;
    f16x8 wf[4];
#pragma unroll
    for (int i = 0; i < 4; ++i)
      wf[i] = load8(Wfc + (size_t)(o0 + m) * kH + (size_t)(w + 8 * i) * 32 + kg * 8);
    f16* ldsH = (f16*)smem;                        // [16][1034] h2[t]
    float* zone = (float*)(smem + kHBytes);        // [8][16][17] per-wave
    unsigned* tagL1h = (unsigned*)(ws + kTagL1 + (size_t)half * 4096);
    const int sb = tid >> 7, so = (tid & 127) * 8;
    const int ob = lane >> 2, op = lane & 3;
    float4 bf4;
    if (w == 0) bf4 = *(const float4*)(bfc + o0 + op * 4);

    for (int t = 1; t <= kSteps; ++t) {
      if (w == 7) {
        const unsigned tgt = (unsigned)t;
        const unsigned* tp = tagL1h + (size_t)lane * 16;
        bool done;
        do {
          done = __all((int)(ld_tag(tp) >= tgt));
          if (!done) __builtin_amdgcn_s_sleep(1);
        } while (!done);
      }
      __syncthreads();
      {
        const char* r2 = ws + kH2Off + ((size_t)t * 2 + half) * kHalfSlot;
        f16x8 b0 = *(const f16x8*)(r2 + (size_t)tid * 16);
        f16x8 b1 = *(const f16x8*)(r2 + (size_t)(tid + 512) * 16);
        f16x8 b2 = *(const f16x8*)(r2 + (size_t)(tid + 1024) * 16);
        f16x8 b3 = *(const f16x8*)(r2 + (size_t)(tid + 1536) * 16);
        *(f16x8*)(ldsH + (sb + 0) * kRowH + so) = b0;
        *(f16x8*)(ldsH + (sb + 4) * kRowH + so) = b1;
        *(f16x8*)(ldsH + (sb + 8) * kRowH + so) = b2;
        *(f16x8*)(ldsH + (sb + 12) * kRowH + so) = b3;
      }
      __syncthreads();
      f32x4 acc = {0.f, 0.f, 0.f, 0.f};
#pragma unroll
      for (int i = 0; i < 4; ++i) {
        f16x8 bf = *(const f16x8*)(ldsH + m * kRowH + (w + 8 * i) * 32 + kg * 8);
        acc = __builtin_amdgcn_mfma_f32_16x16x32_f16(wf[i], bf, acc, 0, 0, 0);
      }
#pragma unroll
      for (int j = 0; j < 4; ++j)
        zone[(w * 16 + lg * 4 + j) * 17 + m] = acc[j];    // per-wave slice
      __syncthreads();
      if (w == 0) {                          // sum 8 slices, + bias, store
        float4 v;
#pragma unroll
        for (int jj = 0; jj < 4; ++jj) {
          float s = 0.f;
#pragma unroll
          for (int ww = 0; ww < 8; ++ww)
            s += zone[(ww * 16 + op * 4 + jj) * 17 + ob];
          ((float*)&v)[jj] = s + ((const float*)&bf4)[jj];
        }
        *(float4*)(out + ((size_t)(half * 16 + ob) * kTR + (t - 1)) * kO +
                   o0 + op * 4) = v;
      }
    }
  }
}

extern "C" void kernel_launch(void* const* d_in, const int* in_sizes, int n_in,
                              void* d_out, int out_size, void* d_ws,
                              size_t ws_size, hipStream_t stream) {
  const float* x    = (const float*)d_in[0];
  const float* Wih0 = (const float*)d_in[1];
  const float* Whh0 = (const float*)d_in[2];
  const float* bih0 = (const float*)d_in[3];
  const float* bhh0 = (const float*)d_in[4];
  const float* Wih1 = (const float*)d_in[5];
  const float* Whh1 = (const float*)d_in[6];
  const float* bih1 = (const float*)d_in[7];
  const float* bhh1 = (const float*)d_in[8];
  const float* Wfc  = (const float*)d_in[9];
  const float* bfc  = (const float*)d_in[10];
  float* out = (float*)d_out;
  char* ws   = (char*)d_ws;

  (void)hipFuncSetAttribute((const void*)lstm_pipe_kernel,
                            hipFuncAttributeMaxDynamicSharedMemorySize,
                            kLdsBytes);

  hipLaunchKernelGGL(lstm_init_kernel, dim3(128), dim3(256), 0, stream, ws);
  hipLaunchKernelGGL(lstm_pipe_kernel, dim3(256), dim3(NTHR), kLdsBytes,
                     stream, x, Wih0, Whh0, bih0, bhh0, Wih1, Whh1, bih1,
                     bhh1, Wfc, bfc, out, ws);
}

// Round 11
// 2371.754 us; speedup vs baseline: 2.7263x; 2.6508x over previous
//
#include <hip/hip_runtime.h>
#include <cstdint>
#include <cstddef>

// ============================================================================
// Persistent fused 2-layer LSTM + FC for MI355X (gfx950) — Round 16:
// EXACT R13 REVERT (2427us config). R14/R15 post-mortem: the regression
// follows the kRowH 1048->1034 stride change, NOT the tag protocol.
// Mechanism: 1034 f16 = 2068B row pitch == 4 (mod 16) -> odd rows lose 16B
// alignment; every f16x8 ds_read_b128/ds_write_b128 at m*kRowH splits into
// double accesses (~2x LDS cost on the MFMA-feed path). The conflict counter
// DROPPED (118.8M->8.2M) because split accesses conflict less — perf rose
// 2.6x anyway. RULE: LDS row pitch must be 16B-aligned; within that class
// stride_dw==12 (mod 32) gives 2-way starts = free (m136). R13's 1048
// (2096B = 131x16, 524dw==12 mod 32) is the aligned optimum.
// This round: byte-identical logic to R13 to re-validate the 2427us ground
// truth on a fresh machine (tests the machine-variance confound).
// ============================================================================

#define NTHR 512

typedef _Float16 f16;
typedef _Float16 f16x8 __attribute__((ext_vector_type(8)));
typedef float f32x4 __attribute__((ext_vector_type(4)));
typedef unsigned long long u64;

namespace {
constexpr int kT = 512, kI = 256, kH = 1024, kO = 512, kTR = 500;
constexpr int kSteps = 500;
constexpr size_t kHalfSlot = 32768;              // 16 b x 1024 u x f16
// ws layout (bytes):
//   [0,2048):        L0 tags half0  (32 x 64B stride)
//   [2048,4096):     L0 tags half1
//   [4096,8192):     L1 tags half0  (64 x 64B stride)
//   [8192,12288):    L1 tags half1
constexpr size_t kTagL0 = 0;
constexpr size_t kTagL1 = 4096;
constexpr size_t kH1Off = 16384;                 // [t][half][b:16][u:1024] f16
constexpr size_t kH2Off = kH1Off + 503ull * 2 * kHalfSlot;
// LDS geometry: 16B-aligned row pitch (2096B = 131x16), stride_dw 524==12
// mod 32 -> 2-way bank starts (free class).
constexpr int kRowH = 1048;
constexpr int kRowX = 264;
constexpr int kLdsBytes = 2 * 16 * kRowH * 2 + 4 * 16 * 17 * 4;  // 71424
}

__device__ __forceinline__ unsigned ld_tag(const void* p) {
  return __hip_atomic_load((const unsigned*)p, __ATOMIC_RELAXED,
                           __HIP_MEMORY_SCOPE_AGENT);
}
__device__ __forceinline__ void st_tag(void* p, unsigned v) {
  __hip_atomic_store((unsigned*)p, v, __ATOMIC_RELAXED,
                     __HIP_MEMORY_SCOPE_AGENT);
}
__device__ __forceinline__ void st_rec_u64(void* p, u64 v) {
  __hip_atomic_store((u64*)p, v, __ATOMIC_RELAXED, __HIP_MEMORY_SCOPE_AGENT);
}
__device__ __forceinline__ float sigmoid_f(float x) {
  return __builtin_amdgcn_rcpf(1.f + __expf(-x));
}
__device__ __forceinline__ float tanh_f(float x) {
  return 1.f - 2.f * __builtin_amdgcn_rcpf(1.f + __expf(2.f * x));
}
__device__ __forceinline__ f16x8 load8(const float* p) {
  f16x8 r;
#pragma unroll
  for (int j = 0; j < 8; ++j) r[j] = (f16)p[j];
  return r;
}
// pack 4 per-lane f16 h-values (lanes lg=0..3 over the same b) into one u64
__device__ __forceinline__ u64 pack4(float h, int lg) {
  f16 hv = (f16)h;
  unsigned short us;
  __builtin_memcpy(&us, &hv, 2);
  unsigned own = us;
  unsigned o1 = __shfl_xor((int)own, 16);
  unsigned p32 = (lg & 1) ? ((o1 & 0xffffu) | (own << 16))
                          : ((own & 0xffffu) | (o1 << 16));
  unsigned o2 = (unsigned)__shfl_xor((int)p32, 32);
  return (lg & 2) ? ((u64)o2 | ((u64)p32 << 32))
                  : ((u64)p32 | ((u64)o2 << 32));
}

__global__ void __launch_bounds__(256, 1) lstm_init_kernel(char* ws) {
  const int gid = blockIdx.x * 256 + threadIdx.x;   // 32768 threads
  unsigned* f = (unsigned*)ws;
  if (gid < 4096) f[gid] = 0u;                      // all tag regions
  u64* r1 = (u64*)(ws + kH1Off);                    // slot 0, both halves
  u64* r2 = (u64*)(ws + kH2Off);
  if (gid < 8192) { r1[gid] = 0ull; r2[gid] = 0ull; }
}

__global__ void __launch_bounds__(NTHR, 1) __attribute__((amdgpu_waves_per_eu(2)))
lstm_pipe_kernel(const float* __restrict__ x,
                 const float* __restrict__ Wih0, const float* __restrict__ Whh0,
                 const float* __restrict__ bih0, const float* __restrict__ bhh0,
                 const float* __restrict__ Wih1, const float* __restrict__ Whh1,
                 const float* __restrict__ bih1, const float* __restrict__ bhh1,
                 const float* __restrict__ Wfc, const float* __restrict__ bfc,
                 float* __restrict__ out, char* __restrict__ ws) {
  const int tid = threadIdx.x;
  const int bk = blockIdx.x;
  const int w = tid >> 6;
  const int lane = tid & 63;
  const int m = lane & 15;                  // A row idx / B col (=batch) / D col
  const int kg = lane >> 4;                 // k-group for A/B frags
  const int lg = lane >> 4;                 // D row group
  const int c = bk & 7, rho = bk >> 3;
  extern __shared__ char smem[];

  if (c < 2) {
    // ===================== L0: h1 recurrence, scope 32 =====================
    const int half = c;
    const int q = m >> 2, g = m & 3;
    const int uA = rho * 32 + 4 * w + q;    // A-row unit
    const int uD = rho * 32 + 4 * w + lg;   // D-row unit (gate math/store)
    f16x8 whh[32], wih[8];
#pragma unroll
    for (int kc = 0; kc < 32; ++kc)
      whh[kc] = load8(Whh0 + (size_t)(g * kH + uA) * kH + kc * 32 + kg * 8);
#pragma unroll
    for (int kx = 0; kx < 8; ++kx)
      wih[kx] = load8(Wih0 + (size_t)(g * kH + uA) * kI + kx * 32 + kg * 8);
    float bias[4];
#pragma unroll
    for (int j = 0; j < 4; ++j) bias[j] = bih0[j * kH + uD] + bhh0[j * kH + uD];
    float cst = 0.f;
    f16* ldsH = (f16*)smem;                             // [16][1048]
    f16* ldsX = (f16*)(smem + 16 * kRowH * 2);          // [16][264]
    unsigned* tagMy = (unsigned*)(ws + kTagL0 + (size_t)half * 2048);
    const int xb = tid >> 5, xcol = (tid & 31) * 8;
    const int sb = tid >> 7, so = (tid & 127) * 8;      // h-stage LDS dest

    for (int t = 1; t <= kSteps; ++t) {
      if (w == 7) {                         // poll own cluster: h1[t-1] ready
        const unsigned tgt = (unsigned)(t - 1);
        const unsigned* tp = tagMy + (size_t)(lane & 31) * 16;
        bool done;
        do {
          done = __all((int)(ld_tag(tp) >= tgt));
          if (!done) __builtin_amdgcn_s_sleep(1);
        } while (!done);
      }
      {                                     // x slice -> LDS (tag-independent)
        f16x8 xv = load8(x + ((size_t)(half * 16 + xb) * kT + (t - 1)) * kI + xcol);
        *(f16x8*)(ldsX + xb * kRowX + xcol) = xv;
      }
      __syncthreads();                      // tags observed by whole block
      {                                     // stage h1[t-1] 32KB -> LDS
        const char* rec = ws + kH1Off + ((size_t)(t - 1) * 2 + half) * kHalfSlot;
        f16x8 h0 = *(const f16x8*)(rec + (size_t)tid * 16);
        f16x8 h1v = *(const f16x8*)(rec + (size_t)(tid + 512) * 16);
        f16x8 h2v = *(const f16x8*)(rec + (size_t)(tid + 1024) * 16);
        f16x8 h3v = *(const f16x8*)(rec + (size_t)(tid + 1536) * 16);
        *(f16x8*)(ldsH + (sb + 0) * kRowH + so) = h0;
        *(f16x8*)(ldsH + (sb + 4) * kRowH + so) = h1v;
        *(f16x8*)(ldsH + (sb + 8) * kRowH + so) = h2v;
        *(f16x8*)(ldsH + (sb + 12) * kRowH + so) = h3v;
      }
      __syncthreads();
      f32x4 acc = {0.f, 0.f, 0.f, 0.f};
#pragma unroll
      for (int kc = 0; kc < 32; ++kc) {
        f16x8 bf = *(const f16x8*)(ldsH + m * kRowH + kc * 32 + kg * 8);
        acc = __builtin_amdgcn_mfma_f32_16x16x32_f16(whh[kc], bf, acc, 0, 0, 0);
      }
#pragma unroll
      for (int kx = 0; kx < 8; ++kx) {
        f16x8 bf = *(const f16x8*)(ldsX + m * kRowX + kx * 32 + kg * 8);
        acc = __builtin_amdgcn_mfma_f32_16x16x32_f16(wih[kx], bf, acc, 0, 0, 0);
      }
      // gates (lane holds 4 gates of unit uD, batch m)
      const float pi = acc[0] + bias[0], pf = acc[1] + bias[1];
      const float pg = acc[2] + bias[2], po = acc[3] + bias[3];
      cst = sigmoid_f(pf) * cst + sigmoid_f(pi) * tanh_f(pg);
      const float h = sigmoid_f(po) * tanh_f(cst);
      const u64 pk = pack4(h, lg);
      if (lane < 16) {                      // b = lane, units rho*32+4w..+3
        st_rec_u64(ws + kH1Off + ((size_t)t * 2 + half) * kHalfSlot +
                       (size_t)lane * 2048 + (size_t)(rho * 32 + 4 * w) * 2,
                   pk);
        asm volatile("s_waitcnt vmcnt(0)" ::: "memory");
      }
      __syncthreads();                      // all waves' records drained
      if (tid == 0) st_tag(tagMy + (size_t)rho * 16, (unsigned)t);
    }

  } else if (c < 6) {
    // ===================== L1: h2 recurrence, scope 64 =====================
    const int half = c & 1;
    const int rank = rho + ((c >= 4) ? 32 : 0);   // 0..63
    const int u0 = rank * 16;
    const int rg = w & 3, kh = w >> 2;            // row-group / K-half
    const int q = m >> 2, g = m & 3;
    const int uA = u0 + 4 * rg + q;
    const int uD = u0 + 4 * rg + lg;
    const float* WA = kh ? Whh1 : Wih1;
    f16x8 wa[32];
#pragma unroll
    for (int kc = 0; kc < 32; ++kc)
      wa[kc] = load8(WA + (size_t)(g * kH + uA) * kH + kc * 32 + kg * 8);
    float bias[4];
#pragma unroll
    for (int j = 0; j < 4; ++j) bias[j] = bih1[j * kH + uD] + bhh1[j * kH + uD];
    float cst = 0.f;                              // live on kh==1 waves
    f16* ldsH1 = (f16*)smem;                      // [16][1048] h1[t]
    f16* ldsH2 = (f16*)(smem + 16 * kRowH * 2);   // [16][1048] h2[t-1]
    float* zone = (float*)(smem + 2 * 16 * kRowH * 2);  // [4][16][17]
    unsigned* tagL0h = (unsigned*)(ws + kTagL0 + (size_t)half * 2048);
    unsigned* tagL1h = (unsigned*)(ws + kTagL1 + (size_t)half * 4096);
    const int sb = tid >> 7, so = (tid & 127) * 8;

    for (int t = 1; t <= kSteps; ++t) {
      if (w == 7) {                         // h1[t] from L0, h2[t-1] own group
        const unsigned tgtA = (unsigned)t, tgtB = (unsigned)(t - 1);
        const unsigned* tpB = tagL1h + (size_t)lane * 16;
        const unsigned* tpA = tagL0h + (size_t)(lane & 31) * 16;
        bool done;
        do {
          bool ok = (ld_tag(tpB) >= tgtB);
          if (lane < 32) ok = ok && (ld_tag(tpA) >= tgtA);
          done = __all((int)ok);
          if (!done) __builtin_amdgcn_s_sleep(1);
        } while (!done);
      }
      __syncthreads();
      {                                     // stage h1[t] + h2[t-1]
        const char* r1 = ws + kH1Off + ((size_t)t * 2 + half) * kHalfSlot;
        const char* r2 = ws + kH2Off + ((size_t)(t - 1) * 2 + half) * kHalfSlot;
        f16x8 a0 = *(const f16x8*)(r1 + (size_t)tid * 16);
        f16x8 a1 = *(const f16x8*)(r1 + (size_t)(tid + 512) * 16);
        f16x8 a2 = *(const f16x8*)(r1 + (size_t)(tid + 1024) * 16);
        f16x8 a3 = *(const f16x8*)(r1 + (size_t)(tid + 1536) * 16);
        f16x8 b0 = *(const f16x8*)(r2 + (size_t)tid * 16);
        f16x8 b1 = *(const f16x8*)(r2 + (size_t)(tid + 512) * 16);
        f16x8 b2 = *(const f16x8*)(r2 + (size_t)(tid + 1024) * 16);
        f16x8 b3 = *(const f16x8*)(r2 + (size_t)(tid + 1536) * 16);
        *(f16x8*)(ldsH1 + (sb + 0) * kRowH + so) = a0;
        *(f16x8*)(ldsH1 + (sb + 4) * kRowH + so) = a1;
        *(f16x8*)(ldsH1 + (sb + 8) * kRowH + so) = a2;
        *(f16x8*)(ldsH1 + (sb + 12) * kRowH + so) = a3;
        *(f16x8*)(ldsH2 + (sb + 0) * kRowH + so) = b0;
        *(f16x8*)(ldsH2 + (sb + 4) * kRowH + so) = b1;
        *(f16x8*)(ldsH2 + (sb + 8) * kRowH + so) = b2;
        *(f16x8*)(ldsH2 + (sb + 12) * kRowH + so) = b3;
      }
      __syncthreads();
      const f16* ldsB = kh ? ldsH2 : ldsH1;
      f32x4 acc = {0.f, 0.f, 0.f, 0.f};
#pragma unroll
      for (int kc = 0; kc < 32; ++kc) {
        f16x8 bf = *(const f16x8*)(ldsB + m * kRowH + kc * 32 + kg * 8);
        acc = __builtin_amdgcn_mfma_f32_16x16x32_f16(wa[kc], bf, acc, 0, 0, 0);
      }
      if (kh == 0) {                        // publish h1-part partials
#pragma unroll
        for (int j = 0; j < 4; ++j)
          zone[(rg * 16 + lg * 4 + j) * 17 + m] = acc[j];
      }
      __syncthreads();                      // zone ready
      if (kh == 1) {                        // combine + gates + store
        const float pi = acc[0] + zone[(rg * 16 + lg * 4 + 0) * 17 + m] + bias[0];
        const float pf = acc[1] + zone[(rg * 16 + lg * 4 + 1) * 17 + m] + bias[1];
        const float pg = acc[2] + zone[(rg * 16 + lg * 4 + 2) * 17 + m] + bias[2];
        const float po = acc[3] + zone[(rg * 16 + lg * 4 + 3) * 17 + m] + bias[3];
        cst = sigmoid_f(pf) * cst + sigmoid_f(pi) * tanh_f(pg);
        const float h = sigmoid_f(po) * tanh_f(cst);
        const u64 pk = pack4(h, lg);
        if (lane < 16) {
          st_rec_u64(ws + kH2Off + ((size_t)t * 2 + half) * kHalfSlot +
                         (size_t)lane * 2048 + (size_t)(u0 + 4 * rg) * 2,
                     pk);
          asm volatile("s_waitcnt vmcnt(0)" ::: "memory");
        }
      }
      __syncthreads();                      // records drained
      if (tid == 0) st_tag(tagL1h + (size_t)rank * 16, (unsigned)t);
    }

  } else {
    // ===================== FC: out = Wfc @ h2[t] + b =======================
    const int half = c - 6;
    const int o0 = rho * 16;
    f16x8 wf[4];
#pragma unroll
    for (int i = 0; i < 4; ++i)
      wf[i] = load8(Wfc + (size_t)(o0 + m) * kH + (size_t)(w + 8 * i) * 32 + kg * 8);
    f16* ldsH = (f16*)smem;                        // [16][1048] h2[t]
    float* zone = (float*)(smem + 16 * kRowH * 2); // [8][16][17] per-wave
    unsigned* tagL1h = (unsigned*)(ws + kTagL1 + (size_t)half * 4096);
    const int sb = tid >> 7, so = (tid & 127) * 8;
    // wave0 store indices
    const int ob = lane >> 2, op = lane & 3;
    float4 bf4;
    if (w == 0) bf4 = *(const float4*)(bfc + o0 + op * 4);

    for (int t = 1; t <= kSteps; ++t) {
      if (w == 7) {
        const unsigned tgt = (unsigned)t;
        const unsigned* tp = tagL1h + (size_t)lane * 16;
        bool done;
        do {
          done = __all((int)(ld_tag(tp) >= tgt));
          if (!done) __builtin_amdgcn_s_sleep(1);
        } while (!done);
      }
      __syncthreads();
      {
        const char* r2 = ws + kH2Off + ((size_t)t * 2 + half) * kHalfSlot;
        f16x8 b0 = *(const f16x8*)(r2 + (size_t)tid * 16);
        f16x8 b1 = *(const f16x8*)(r2 + (size_t)(tid + 512) * 16);
        f16x8 b2 = *(const f16x8*)(r2 + (size_t)(tid + 1024) * 16);
        f16x8 b3 = *(const f16x8*)(r2 + (size_t)(tid + 1536) * 16);
        *(f16x8*)(ldsH + (sb + 0) * kRowH + so) = b0;
        *(f16x8*)(ldsH + (sb + 4) * kRowH + so) = b1;
        *(f16x8*)(ldsH + (sb + 8) * kRowH + so) = b2;
        *(f16x8*)(ldsH + (sb + 12) * kRowH + so) = b3;
      }
      __syncthreads();
      f32x4 acc = {0.f, 0.f, 0.f, 0.f};
#pragma unroll
      for (int i = 0; i < 4; ++i) {
        f16x8 bf = *(const f16x8*)(ldsH + m * kRowH + (w + 8 * i) * 32 + kg * 8);
        acc = __builtin_amdgcn_mfma_f32_16x16x32_f16(wf[i], bf, acc, 0, 0, 0);
      }
#pragma unroll
      for (int j = 0; j < 4; ++j)
        zone[(w * 16 + lg * 4 + j) * 17 + m] = acc[j];    // per-wave slice
      __syncthreads();
      if (w == 0) {                          // sum 8 slices, + bias, store
        float4 v;
#pragma unroll
        for (int jj = 0; jj < 4; ++jj) {
          float s = 0.f;
#pragma unroll
          for (int ww = 0; ww < 8; ++ww)
            s += zone[(ww * 16 + op * 4 + jj) * 17 + ob];
          ((float*)&v)[jj] = s + ((const float*)&bf4)[jj];
        }
        *(float4*)(out + ((size_t)(half * 16 + ob) * kTR + (t - 1)) * kO +
                   o0 + op * 4) = v;
      }
    }
  }
}

extern "C" void kernel_launch(void* const* d_in, const int* in_sizes, int n_in,
                              void* d_out, int out_size, void* d_ws,
                              size_t ws_size, hipStream_t stream) {
  const float* x    = (const float*)d_in[0];
  const float* Wih0 = (const float*)d_in[1];
  const float* Whh0 = (const float*)d_in[2];
  const float* bih0 = (const float*)d_in[3];
  const float* bhh0 = (const float*)d_in[4];
  const float* Wih1 = (const float*)d_in[5];
  const float* Whh1 = (const float*)d_in[6];
  const float* bih1 = (const float*)d_in[7];
  const float* bhh1 = (const float*)d_in[8];
  const float* Wfc  = (const float*)d_in[9];
  const float* bfc  = (const float*)d_in[10];
  float* out = (float*)d_out;
  char* ws   = (char*)d_ws;

  (void)hipFuncSetAttribute((const void*)lstm_pipe_kernel,
                            hipFuncAttributeMaxDynamicSharedMemorySize,
                            kLdsBytes);

  hipLaunchKernelGGL(lstm_init_kernel, dim3(128), dim3(256), 0, stream, ws);
  hipLaunchKernelGGL(lstm_pipe_kernel, dim3(256), dim3(NTHR), kLdsBytes,
                     stream, x, Wih0, Whh0, bih0, bhh0, Wih1, Whh1, bih1,
                     bhh1, Wfc, bfc, out, ws);
}

// Round 12
// 2280.900 us; speedup vs baseline: 2.8349x; 1.0398x over previous
//
#include <hip/hip_runtime.h>
#include <cstdint>
#include <cstddef>

// ============================================================================
// Persistent fused 2-layer LSTM + FC for MI355X (gfx950) — Round 17:
// L1 CYCLE SHORTENING. R16 re-validated 2372us ground truth (R14/R15 were
// the misaligned 2068B LDS pitch; pitch must be 16B-aligned, 2-way starts
// free). Remaining 4.6us/step = the two LLC recurrence cycles; L1's h2 cycle
// is structurally longest (waits h1[t]+h2[t-1] tags, stages 64KB serially,
// extra zone barrier). This round restructures ONLY the L1 branch:
//   1. Poll h2 tags first (own-layer binding wait) -> barrier.
//   2. All threads load h2 records to regs; w7 polls h1 tags CONCURRENTLY
//      (h1 wait hides under h2 load latency); write h2 -> LDS2; barrier.
//   3. Role-split: kh1 waves run h2-side MFMAs + zone writes WHILE kh0
//      waves stage the full 32KB h1 tile (8x16B per thread); barrier.
//   4. kh0: h1-side MFMAs + zone combine + gates (c-state now on kh0) +
//      h2[t] record store + drain; barrier; tid0 tags.
// h2-critical path loses the h1 wait and half the staged bytes; staging
// overlaps compute. Same 4 barriers/step, same single-writer tag protocol.
// L0, FC, tags, layouts: byte-identical to R16/R13.
// ============================================================================

#define NTHR 512

typedef _Float16 f16;
typedef _Float16 f16x8 __attribute__((ext_vector_type(8)));
typedef float f32x4 __attribute__((ext_vector_type(4)));
typedef unsigned long long u64;

namespace {
constexpr int kT = 512, kI = 256, kH = 1024, kO = 512, kTR = 500;
constexpr int kSteps = 500;
constexpr size_t kHalfSlot = 32768;              // 16 b x 1024 u x f16
constexpr size_t kTagL0 = 0;
constexpr size_t kTagL1 = 4096;
constexpr size_t kH1Off = 16384;                 // [t][half][b:16][u:1024] f16
constexpr size_t kH2Off = kH1Off + 503ull * 2 * kHalfSlot;
// LDS geometry: 16B-aligned row pitch (2096B = 131x16), stride_dw 524==12
// mod 32 -> 2-way bank starts (free class).
constexpr int kRowH = 1048;
constexpr int kRowX = 264;
constexpr int kLdsBytes = 2 * 16 * kRowH * 2 + 4 * 16 * 17 * 4;  // 71424
}

__device__ __forceinline__ unsigned ld_tag(const void* p) {
  return __hip_atomic_load((const unsigned*)p, __ATOMIC_RELAXED,
                           __HIP_MEMORY_SCOPE_AGENT);
}
__device__ __forceinline__ void st_tag(void* p, unsigned v) {
  __hip_atomic_store((unsigned*)p, v, __ATOMIC_RELAXED,
                     __HIP_MEMORY_SCOPE_AGENT);
}
__device__ __forceinline__ void st_rec_u64(void* p, u64 v) {
  __hip_atomic_store((u64*)p, v, __ATOMIC_RELAXED, __HIP_MEMORY_SCOPE_AGENT);
}
__device__ __forceinline__ float sigmoid_f(float x) {
  return __builtin_amdgcn_rcpf(1.f + __expf(-x));
}
__device__ __forceinline__ float tanh_f(float x) {
  return 1.f - 2.f * __builtin_amdgcn_rcpf(1.f + __expf(2.f * x));
}
__device__ __forceinline__ f16x8 load8(const float* p) {
  f16x8 r;
#pragma unroll
  for (int j = 0; j < 8; ++j) r[j] = (f16)p[j];
  return r;
}
// pack 4 per-lane f16 h-values (lanes lg=0..3 over the same b) into one u64
__device__ __forceinline__ u64 pack4(float h, int lg) {
  f16 hv = (f16)h;
  unsigned short us;
  __builtin_memcpy(&us, &hv, 2);
  unsigned own = us;
  unsigned o1 = __shfl_xor((int)own, 16);
  unsigned p32 = (lg & 1) ? ((o1 & 0xffffu) | (own << 16))
                          : ((own & 0xffffu) | (o1 << 16));
  unsigned o2 = (unsigned)__shfl_xor((int)p32, 32);
  return (lg & 2) ? ((u64)o2 | ((u64)p32 << 32))
                  : ((u64)p32 | ((u64)o2 << 32));
}

__global__ void __launch_bounds__(256, 1) lstm_init_kernel(char* ws) {
  const int gid = blockIdx.x * 256 + threadIdx.x;   // 32768 threads
  unsigned* f = (unsigned*)ws;
  if (gid < 4096) f[gid] = 0u;                      // all tag regions
  u64* r1 = (u64*)(ws + kH1Off);                    // slot 0, both halves
  u64* r2 = (u64*)(ws + kH2Off);
  if (gid < 8192) { r1[gid] = 0ull; r2[gid] = 0ull; }
}

__global__ void __launch_bounds__(NTHR, 1) __attribute__((amdgpu_waves_per_eu(2)))
lstm_pipe_kernel(const float* __restrict__ x,
                 const float* __restrict__ Wih0, const float* __restrict__ Whh0,
                 const float* __restrict__ bih0, const float* __restrict__ bhh0,
                 const float* __restrict__ Wih1, const float* __restrict__ Whh1,
                 const float* __restrict__ bih1, const float* __restrict__ bhh1,
                 const float* __restrict__ Wfc, const float* __restrict__ bfc,
                 float* __restrict__ out, char* __restrict__ ws) {
  const int tid = threadIdx.x;
  const int bk = blockIdx.x;
  const int w = tid >> 6;
  const int lane = tid & 63;
  const int m = lane & 15;                  // A row idx / B col (=batch) / D col
  const int kg = lane >> 4;                 // k-group for A/B frags
  const int lg = lane >> 4;                 // D row group
  const int c = bk & 7, rho = bk >> 3;
  extern __shared__ char smem[];

  if (c < 2) {
    // ===================== L0: h1 recurrence, scope 32 =====================
    const int half = c;
    const int q = m >> 2, g = m & 3;
    const int uA = rho * 32 + 4 * w + q;    // A-row unit
    const int uD = rho * 32 + 4 * w + lg;   // D-row unit (gate math/store)
    f16x8 whh[32], wih[8];
#pragma unroll
    for (int kc = 0; kc < 32; ++kc)
      whh[kc] = load8(Whh0 + (size_t)(g * kH + uA) * kH + kc * 32 + kg * 8);
#pragma unroll
    for (int kx = 0; kx < 8; ++kx)
      wih[kx] = load8(Wih0 + (size_t)(g * kH + uA) * kI + kx * 32 + kg * 8);
    float bias[4];
#pragma unroll
    for (int j = 0; j < 4; ++j) bias[j] = bih0[j * kH + uD] + bhh0[j * kH + uD];
    float cst = 0.f;
    f16* ldsH = (f16*)smem;                             // [16][1048]
    f16* ldsX = (f16*)(smem + 16 * kRowH * 2);          // [16][264]
    unsigned* tagMy = (unsigned*)(ws + kTagL0 + (size_t)half * 2048);
    const int xb = tid >> 5, xcol = (tid & 31) * 8;
    const int sb = tid >> 7, so = (tid & 127) * 8;      // h-stage LDS dest

    for (int t = 1; t <= kSteps; ++t) {
      if (w == 7) {                         // poll own cluster: h1[t-1] ready
        const unsigned tgt = (unsigned)(t - 1);
        const unsigned* tp = tagMy + (size_t)(lane & 31) * 16;
        bool done;
        do {
          done = __all((int)(ld_tag(tp) >= tgt));
          if (!done) __builtin_amdgcn_s_sleep(1);
        } while (!done);
      }
      {                                     // x slice -> LDS (tag-independent)
        f16x8 xv = load8(x + ((size_t)(half * 16 + xb) * kT + (t - 1)) * kI + xcol);
        *(f16x8*)(ldsX + xb * kRowX + xcol) = xv;
      }
      __syncthreads();                      // tags observed by whole block
      {                                     // stage h1[t-1] 32KB -> LDS
        const char* rec = ws + kH1Off + ((size_t)(t - 1) * 2 + half) * kHalfSlot;
        f16x8 h0 = *(const f16x8*)(rec + (size_t)tid * 16);
        f16x8 h1v = *(const f16x8*)(rec + (size_t)(tid + 512) * 16);
        f16x8 h2v = *(const f16x8*)(rec + (size_t)(tid + 1024) * 16);
        f16x8 h3v = *(const f16x8*)(rec + (size_t)(tid + 1536) * 16);
        *(f16x8*)(ldsH + (sb + 0) * kRowH + so) = h0;
        *(f16x8*)(ldsH + (sb + 4) * kRowH + so) = h1v;
        *(f16x8*)(ldsH + (sb + 8) * kRowH + so) = h2v;
        *(f16x8*)(ldsH + (sb + 12) * kRowH + so) = h3v;
      }
      __syncthreads();
      f32x4 acc = {0.f, 0.f, 0.f, 0.f};
#pragma unroll
      for (int kc = 0; kc < 32; ++kc) {
        f16x8 bf = *(const f16x8*)(ldsH + m * kRowH + kc * 32 + kg * 8);
        acc = __builtin_amdgcn_mfma_f32_16x16x32_f16(whh[kc], bf, acc, 0, 0, 0);
      }
#pragma unroll
      for (int kx = 0; kx < 8; ++kx) {
        f16x8 bf = *(const f16x8*)(ldsX + m * kRowX + kx * 32 + kg * 8);
        acc = __builtin_amdgcn_mfma_f32_16x16x32_f16(wih[kx], bf, acc, 0, 0, 0);
      }
      // gates (lane holds 4 gates of unit uD, batch m)
      const float pi = acc[0] + bias[0], pf = acc[1] + bias[1];
      const float pg = acc[2] + bias[2], po = acc[3] + bias[3];
      cst = sigmoid_f(pf) * cst + sigmoid_f(pi) * tanh_f(pg);
      const float h = sigmoid_f(po) * tanh_f(cst);
      const u64 pk = pack4(h, lg);
      if (lane < 16) {                      // b = lane, units rho*32+4w..+3
        st_rec_u64(ws + kH1Off + ((size_t)t * 2 + half) * kHalfSlot +
                       (size_t)lane * 2048 + (size_t)(rho * 32 + 4 * w) * 2,
                   pk);
        asm volatile("s_waitcnt vmcnt(0)" ::: "memory");
      }
      __syncthreads();                      // all waves' records drained
      if (tid == 0) st_tag(tagMy + (size_t)rho * 16, (unsigned)t);
    }

  } else if (c < 6) {
    // ============ L1: h2 recurrence, scope 64, SHORTENED CYCLE =============
    const int half = c & 1;
    const int rank = rho + ((c >= 4) ? 32 : 0);   // 0..63
    const int u0 = rank * 16;
    const int rg = w & 3, kh = w >> 2;            // row-group / K-side
    const int q = m >> 2, g = m & 3;
    const int uA = u0 + 4 * rg + q;
    const int uD = u0 + 4 * rg + lg;
    const float* WA = kh ? Whh1 : Wih1;           // kh1 = h2 side, kh0 = h1
    f16x8 wa[32];
#pragma unroll
    for (int kc = 0; kc < 32; ++kc)
      wa[kc] = load8(WA + (size_t)(g * kH + uA) * kH + kc * 32 + kg * 8);
    float bias[4];                                 // used by kh0 (gate waves)
#pragma unroll
    for (int j = 0; j < 4; ++j) bias[j] = bih1[j * kH + uD] + bhh1[j * kH + uD];
    float cst = 0.f;                               // c-state lives on kh0 now
    f16* ldsH1 = (f16*)smem;                       // [16][1048] h1[t]
    f16* ldsH2 = (f16*)(smem + 16 * kRowH * 2);    // [16][1048] h2[t-1]
    float* zone = (float*)(smem + 2 * 16 * kRowH * 2);  // [4][16][17] h2-part
    unsigned* tagL0h = (unsigned*)(ws + kTagL0 + (size_t)half * 2048);
    unsigned* tagL1h = (unsigned*)(ws + kTagL1 + (size_t)half * 4096);
    const int sb = tid >> 7, so = (tid & 127) * 8;

    for (int t = 1; t <= kSteps; ++t) {
      // ---- phase 1: own-layer wait only (h2[t-1] tags)
      if (w == 7) {
        const unsigned tgtB = (unsigned)(t - 1);
        const unsigned* tpB = tagL1h + (size_t)lane * 16;
        bool done;
        do {
          done = __all((int)(ld_tag(tpB) >= tgtB));
          if (!done) __builtin_amdgcn_s_sleep(1);
        } while (!done);
      }
      __syncthreads();                      // B-tags observed
      // ---- phase 2: h2 -> regs (all threads); w7 polls h1 tags under the
      //      load latency; then write h2 -> LDS2.
      {
        const char* r2 = ws + kH2Off + ((size_t)(t - 1) * 2 + half) * kHalfSlot;
        f16x8 b0 = *(const f16x8*)(r2 + (size_t)tid * 16);
        f16x8 b1 = *(const f16x8*)(r2 + (size_t)(tid + 512) * 16);
        f16x8 b2 = *(const f16x8*)(r2 + (size_t)(tid + 1024) * 16);
        f16x8 b3 = *(const f16x8*)(r2 + (size_t)(tid + 1536) * 16);
        if (w == 7) {                       // h1[t] from L0 (usually ready)
          const unsigned tgtA = (unsigned)t;
          const unsigned* tpA = tagL0h + (size_t)(lane & 31) * 16;
          bool done;
          do {
            done = __all((int)(ld_tag(tpA) >= tgtA));
            if (!done) __builtin_amdgcn_s_sleep(1);
          } while (!done);
        }
        *(f16x8*)(ldsH2 + (sb + 0) * kRowH + so) = b0;
        *(f16x8*)(ldsH2 + (sb + 4) * kRowH + so) = b1;
        *(f16x8*)(ldsH2 + (sb + 8) * kRowH + so) = b2;
        *(f16x8*)(ldsH2 + (sb + 12) * kRowH + so) = b3;
      }
      __syncthreads();                      // LDS2 ready + A-tags observed
      // ---- phase 3: kh1 computes h2-side + zone; kh0 stages h1 32KB
      if (kh == 1) {
        f32x4 acc = {0.f, 0.f, 0.f, 0.f};
#pragma unroll
        for (int kc = 0; kc < 32; ++kc) {
          f16x8 bf = *(const f16x8*)(ldsH2 + m * kRowH + kc * 32 + kg * 8);
          acc = __builtin_amdgcn_mfma_f32_16x16x32_f16(wa[kc], bf, acc, 0, 0, 0);
        }
#pragma unroll
        for (int j = 0; j < 4; ++j)
          zone[(rg * 16 + lg * 4 + j) * 17 + m] = acc[j];
      } else {
        const char* r1 = ws + kH1Off + ((size_t)t * 2 + half) * kHalfSlot;
        f16x8 a[8];
#pragma unroll
        for (int j = 0; j < 8; ++j)
          a[j] = *(const f16x8*)(r1 + ((size_t)(j * 256 + tid)) * 16);
#pragma unroll
        for (int j = 0; j < 8; ++j) {
          const int i = j * 256 + tid;
          *(f16x8*)(ldsH1 + (i >> 7) * kRowH + (i & 127) * 8) = a[j];
        }
      }
      __syncthreads();                      // zone + LDS1 ready
      // ---- phase 4: kh0 h1-side MFMAs + combine + gates + store + drain
      if (kh == 0) {
        f32x4 acc = {0.f, 0.f, 0.f, 0.f};
#pragma unroll
        for (int kc = 0; kc < 32; ++kc) {
          f16x8 bf = *(const f16x8*)(ldsH1 + m * kRowH + kc * 32 + kg * 8);
          acc = __builtin_amdgcn_mfma_f32_16x16x32_f16(wa[kc], bf, acc, 0, 0, 0);
        }
        const float pi = acc[0] + zone[(rg * 16 + lg * 4 + 0) * 17 + m] + bias[0];
        const float pf = acc[1] + zone[(rg * 16 + lg * 4 + 1) * 17 + m] + bias[1];
        const float pg = acc[2] + zone[(rg * 16 + lg * 4 + 2) * 17 + m] + bias[2];
        const float po = acc[3] + zone[(rg * 16 + lg * 4 + 3) * 17 + m] + bias[3];
        cst = sigmoid_f(pf) * cst + sigmoid_f(pi) * tanh_f(pg);
        const float h = sigmoid_f(po) * tanh_f(cst);
        const u64 pk = pack4(h, lg);
        if (lane < 16) {
          st_rec_u64(ws + kH2Off + ((size_t)t * 2 + half) * kHalfSlot +
                         (size_t)lane * 2048 + (size_t)(u0 + 4 * rg) * 2,
                     pk);
          asm volatile("s_waitcnt vmcnt(0)" ::: "memory");
        }
      }
      __syncthreads();                      // kh0 records drained
      if (tid == 0) st_tag(tagL1h + (size_t)rank * 16, (unsigned)t);
    }

  } else {
    // ===================== FC: out = Wfc @ h2[t] + b =======================
    const int half = c - 6;
    const int o0 = rho * 16;
    f16x8 wf[4];
#pragma unroll
    for (int i = 0; i < 4; ++i)
      wf[i] = load8(Wfc + (size_t)(o0 + m) * kH + (size_t)(w + 8 * i) * 32 + kg * 8);
    f16* ldsH = (f16*)smem;                        // [16][1048] h2[t]
    float* zone = (float*)(smem + 16 * kRowH * 2); // [8][16][17] per-wave
    unsigned* tagL1h = (unsigned*)(ws + kTagL1 + (size_t)half * 4096);
    const int sb = tid >> 7, so = (tid & 127) * 8;
    // wave0 store indices
    const int ob = lane >> 2, op = lane & 3;
    float4 bf4;
    if (w == 0) bf4 = *(const float4*)(bfc + o0 + op * 4);

    for (int t = 1; t <= kSteps; ++t) {
      if (w == 7) {
        const unsigned tgt = (unsigned)t;
        const unsigned* tp = tagL1h + (size_t)lane * 16;
        bool done;
        do {
          done = __all((int)(ld_tag(tp) >= tgt));
          if (!done) __builtin_amdgcn_s_sleep(1);
        } while (!done);
      }
      __syncthreads();
      {
        const char* r2 = ws + kH2Off + ((size_t)t * 2 + half) * kHalfSlot;
        f16x8 b0 = *(const f16x8*)(r2 + (size_t)tid * 16);
        f16x8 b1 = *(const f16x8*)(r2 + (size_t)(tid + 512) * 16);
        f16x8 b2 = *(const f16x8*)(r2 + (size_t)(tid + 1024) * 16);
        f16x8 b3 = *(const f16x8*)(r2 + (size_t)(tid + 1536) * 16);
        *(f16x8*)(ldsH + (sb + 0) * kRowH + so) = b0;
        *(f16x8*)(ldsH + (sb + 4) * kRowH + so) = b1;
        *(f16x8*)(ldsH + (sb + 8) * kRowH + so) = b2;
        *(f16x8*)(ldsH + (sb + 12) * kRowH + so) = b3;
      }
      __syncthreads();
      f32x4 acc = {0.f, 0.f, 0.f, 0.f};
#pragma unroll
      for (int i = 0; i < 4; ++i) {
        f16x8 bf = *(const f16x8*)(ldsH + m * kRowH + (w + 8 * i) * 32 + kg * 8);
        acc = __builtin_amdgcn_mfma_f32_16x16x32_f16(wf[i], bf, acc, 0, 0, 0);
      }
#pragma unroll
      for (int j = 0; j < 4; ++j)
        zone[(w * 16 + lg * 4 + j) * 17 + m] = acc[j];    // per-wave slice
      __syncthreads();
      if (w == 0) {                          // sum 8 slices, + bias, store
        float4 v;
#pragma unroll
        for (int jj = 0; jj < 4; ++jj) {
          float s = 0.f;
#pragma unroll
          for (int ww = 0; ww < 8; ++ww)
            s += zone[(ww * 16 + op * 4 + jj) * 17 + ob];
          ((float*)&v)[jj] = s + ((const float*)&bf4)[jj];
        }
        *(float4*)(out + ((size_t)(half * 16 + ob) * kTR + (t - 1)) * kO +
                   o0 + op * 4) = v;
      }
    }
  }
}

extern "C" void kernel_launch(void* const* d_in, const int* in_sizes, int n_in,
                              void* d_out, int out_size, void* d_ws,
                              size_t ws_size, hipStream_t stream) {
  const float* x    = (const float*)d_in[0];
  const float* Wih0 = (const float*)d_in[1];
  const float* Whh0 = (const float*)d_in[2];
  const float* bih0 = (const float*)d_in[3];
  const float* bhh0 = (const float*)d_in[4];
  const float* Wih1 = (const float*)d_in[5];
  const float* Whh1 = (const float*)d_in[6];
  const float* bih1 = (const float*)d_in[7];
  const float* bhh1 = (const float*)d_in[8];
  const float* Wfc  = (const float*)d_in[9];
  const float* bfc  = (const float*)d_in[10];
  float* out = (float*)d_out;
  char* ws   = (char*)d_ws;

  (void)hipFuncSetAttribute((const void*)lstm_pipe_kernel,
                            hipFuncAttributeMaxDynamicSharedMemorySize,
                            kLdsBytes);

  hipLaunchKernelGGL(lstm_init_kernel, dim3(128), dim3(256), 0, stream, ws);
  hipLaunchKernelGGL(lstm_pipe_kernel, dim3(256), dim3(NTHR), kLdsBytes,
                     stream, x, Wih0, Whh0, bih0, bhh0, Wih1, Whh1, bih1,
                     bhh1, Wfc, bfc, out, ws);
}